// Round 11
// baseline (262.518 us; speedup 1.0000x reference)
//
#include <hip/hip_runtime.h>
#include <cstdint>

#define ALPHA 0.2f

constexpr int NB = 8;
constexpr int NN = 2048;
constexpr int NF = 256;

typedef __attribute__((ext_vector_type(8))) short bf16x8;
typedef __attribute__((ext_vector_type(4))) float f32x4;

__device__ __forceinline__ float bf2f(unsigned short u) {
    union { unsigned int i; float f; } v;
    v.i = ((unsigned int)u) << 16;
    return v.f;
}
__device__ __forceinline__ unsigned short f2bf(float f) {
    union { float f; unsigned int i; } v;
    v.f = f;
    v.i += 0x7fffu + ((v.i >> 16) & 1);  // round-to-nearest-even
    return (unsigned short)(v.i >> 16);
}
// pack two non-negative floats to packed bf16 pair (round-half-up), 3 ops
__device__ __forceinline__ unsigned int pk2bf(float lo, float hi) {
    union { float f; unsigned int u; } a, b;
    a.f = lo; b.f = hi;
    return __builtin_amdgcn_perm(b.u + 0x8000u, a.u + 0x8000u, 0x07060302u);
}

// ---------------------------------------------------------------------------
// Kernel 0: WT[f][k] = bf16(W[k][f]) transpose+cast; also zero s1/s2
// ---------------------------------------------------------------------------
__global__ __launch_bounds__(256) void k_wt(const float* __restrict__ W,
                                            unsigned short* __restrict__ WT,
                                            float* __restrict__ s1,
                                            float* __restrict__ s2) {
    const int t = threadIdx.x;
    const int gid = blockIdx.x * 256 + t;
    s1[gid] = 0.f;
    s2[gid] = 0.f;
    const int k = blockIdx.x * 4 + (t >> 6);
    const int f0 = (t & 63) * 4;
    const float4 w = *(const float4*)&W[k * NF + f0];
    WT[(f0 + 0) * NF + k] = f2bf(w.x);
    WT[(f0 + 1) * NF + k] = f2bf(w.y);
    WT[(f0 + 2) * NF + k] = f2bf(w.z);
    WT[(f0 + 3) * NF + k] = f2bf(w.w);
}

// ---------------------------------------------------------------------------
// Kernel 1: WhT = (h @ W)^T per batch, bf16 MFMA; fused s1/s2 epilogue.
// (unchanged — proven correct, ~6-8 us)
// ---------------------------------------------------------------------------
__global__ __launch_bounds__(256, 4) void k_wh(const float* __restrict__ h,
                                               const unsigned short* __restrict__ WT,
                                               const float* __restrict__ a,
                                               unsigned short* __restrict__ WhT,
                                               float* __restrict__ s1,
                                               float* __restrict__ s2) {
    __shared__ __align__(16) unsigned short As[64][72];  // [row][k] bf16
    __shared__ __align__(16) unsigned short Bs[64][72];  // [f][k]  bf16
    const int tid = threadIdx.x;
    const int lane = tid & 63;
    const int l16 = lane & 15;
    const int quad = lane >> 4;
    const int wave = tid >> 6;

    const int p = blockIdx.x;
    const int xcd = p & 7;
    const int q = p >> 3;                       // 0..127
    const int rowTile = xcd + (q >> 2) * 8;     // 0..255
    const int row0 = rowTile * 64;
    const int col0 = (q & 3) * 64;

    const int bb = row0 >> 11;
    const int n0 = row0 & (NN - 1);
    const int mb = (wave & 1) * 32;
    const int nb = (wave >> 1) * 32;

    f32x4 acc[2][2];
#pragma unroll
    for (int mf = 0; mf < 2; ++mf)
#pragma unroll
        for (int nf = 0; nf < 2; ++nf) acc[mf][nf] = (f32x4){0.f, 0.f, 0.f, 0.f};

    const int r0 = tid >> 4;          // 0..15  (+16 per group)
    const int k4 = (tid & 15) * 4;    // 0..60
    const int f0w = tid >> 3;         // 0..31  (+32 per group)
    const int k8 = (tid & 7) * 8;     // 0..56

    const float* hP = &h[(size_t)(row0 + r0) * NF + k4];
    const unsigned short* wP = &WT[(size_t)(col0 + f0w) * NF + k8];

    float4 h0, h1, h2, h3;
    uint4 wv0, wv1;

#define LOADW(K0)                                                      \
    do {                                                               \
        h0 = *(const float4*)&hP[(size_t)(0 * 16) * NF + (K0)];        \
        h1 = *(const float4*)&hP[(size_t)(1 * 16) * NF + (K0)];        \
        h2 = *(const float4*)&hP[(size_t)(2 * 16) * NF + (K0)];        \
        h3 = *(const float4*)&hP[(size_t)(3 * 16) * NF + (K0)];        \
        wv0 = *(const uint4*)&wP[(K0)];                                \
        wv1 = *(const uint4*)&wP[(size_t)32 * NF + (K0)];              \
    } while (0)

    LOADW(0);

    for (int k0 = 0; k0 < NF; k0 += 64) {
        ushort4 o;
        o.x = f2bf(h0.x); o.y = f2bf(h0.y); o.z = f2bf(h0.z); o.w = f2bf(h0.w);
        *(ushort4*)&As[r0 + 0][k4] = o;
        o.x = f2bf(h1.x); o.y = f2bf(h1.y); o.z = f2bf(h1.z); o.w = f2bf(h1.w);
        *(ushort4*)&As[r0 + 16][k4] = o;
        o.x = f2bf(h2.x); o.y = f2bf(h2.y); o.z = f2bf(h2.z); o.w = f2bf(h2.w);
        *(ushort4*)&As[r0 + 32][k4] = o;
        o.x = f2bf(h3.x); o.y = f2bf(h3.y); o.z = f2bf(h3.z); o.w = f2bf(h3.w);
        *(ushort4*)&As[r0 + 48][k4] = o;
        *(uint4*)&Bs[f0w][k8] = wv0;
        *(uint4*)&Bs[f0w + 32][k8] = wv1;
        __syncthreads();
        if (k0 + 64 < NF) LOADW(k0 + 64);
#pragma unroll
        for (int ks = 0; ks < 64; ks += 32) {
            bf16x8 av[2], bv[2];
#pragma unroll
            for (int mf = 0; mf < 2; ++mf)
                av[mf] = *(const bf16x8*)&As[mb + mf * 16 + l16][ks + quad * 8];
#pragma unroll
            for (int nf = 0; nf < 2; ++nf)
                bv[nf] = *(const bf16x8*)&Bs[nb + nf * 16 + l16][ks + quad * 8];
#pragma unroll
            for (int mf = 0; mf < 2; ++mf)
#pragma unroll
                for (int nf = 0; nf < 2; ++nf)
                    acc[mf][nf] = __builtin_amdgcn_mfma_f32_16x16x32_bf16(
                        av[mf], bv[nf], acc[mf][nf], 0, 0, 0);
        }
        __syncthreads();
    }
#undef LOADW

#pragma unroll
    for (int mf = 0; mf < 2; ++mf) {
#pragma unroll
        for (int nf = 0; nf < 2; ++nf) {
            const size_t f = col0 + nb + nf * 16 + l16;
            const int nr = n0 + mb + mf * 16 + quad * 4;
            ushort4 o;
            o.x = f2bf(acc[mf][nf][0]);
            o.y = f2bf(acc[mf][nf][1]);
            o.z = f2bf(acc[mf][nf][2]);
            o.w = f2bf(acc[mf][nf][3]);
            *(ushort4*)&WhT[((size_t)bb * NF + f) * NN + nr] = o;
        }
    }

    float a1v[2], a2v[2];
#pragma unroll
    for (int nf = 0; nf < 2; ++nf) {
        const int f = col0 + nb + nf * 16 + l16;
        a1v[nf] = a[f];
        a2v[nf] = a[NF + f];
    }
#pragma unroll
    for (int mf = 0; mf < 2; ++mf) {
#pragma unroll
        for (int r = 0; r < 4; ++r) {
            float p1 = acc[mf][0][r] * a1v[0] + acc[mf][1][r] * a1v[1];
            float p2 = acc[mf][0][r] * a2v[0] + acc[mf][1][r] * a2v[1];
            p1 += __shfl_xor(p1, 1); p2 += __shfl_xor(p2, 1);
            p1 += __shfl_xor(p1, 2); p2 += __shfl_xor(p2, 2);
            p1 += __shfl_xor(p1, 4); p2 += __shfl_xor(p2, 4);
            p1 += __shfl_xor(p1, 8); p2 += __shfl_xor(p2, 8);
            if (l16 == 0) {
                const int n = n0 + mb + mf * 16 + quad * 4 + r;
                atomicAdd(&s1[bb * NN + n], p1);
                atomicAdd(&s2[bb * NN + n], p2);
            }
        }
    }
}

// ---------------------------------------------------------------------------
// Kernel 2: fused masked softmax + attn @ Wh.
// r9 pipeline with the LDS-bandwidth term removed:
//  * NO WhsT staging: each wave register-prefetches its 8 B-fragments
//    (16 contiguous bytes of WhT[b][f][j], L2-resident, XCD-pinned) ONE
//    TILE AHEAD via 2x-unrolled loop with named even/odd register sets.
//    LDS traffic/iter/CU: 168 KB -> ~9 KB (was ~1300cy of the ~2775cy
//    per-iter critical path).
//  * Pb double-buffered -> ONE __syncthreads per iteration (safe: full
//    drain means reader's ds_reads finish before it passes bar(t+1), and
//    the t+2 writer writes after bar(t+1)).
//  * adj/s2 prefetched one tile ahead; register row-sums (r9).
// Grid 512 = 8 b x 64 q-tiles, one batch per XCD, 256 thr, LDS 9.4 KB.
// ---------------------------------------------------------------------------
__global__ __launch_bounds__(256, 2) void k_attn(const unsigned short* __restrict__ WhT,
                                                 const int* __restrict__ adj,
                                                 const float* __restrict__ s1g,
                                                 const float* __restrict__ s2g,
                                                 float* __restrict__ out) {
    __shared__ __align__(16) unsigned short Pb[2][32][72];  // [buf][i][j]
    __shared__ float l_s[32];

    const int tid = threadIdx.x;
    const int lane = tid & 63;
    const int l16 = lane & 15;
    const int quad = lane >> 4;
    const int wave = tid >> 6;
    const int bb = blockIdx.x & 7;           // one batch per XCD
    const int i0 = (blockIdx.x >> 3) * 32;   // q-tile base

    f32x4 acc[2][4];
#pragma unroll
    for (int m = 0; m < 2; ++m)
#pragma unroll
        for (int nf = 0; nf < 4; ++nf) acc[m][nf] = (f32x4){0.f, 0.f, 0.f, 0.f};

    const size_t whtBase = (size_t)bb * NF * NN;
    const size_t adjBase = (size_t)bb * NN * NN;

    // P-compute geometry: thread (pIr,pKq) covers rows {pIr, pIr+16}, 4 j's
    const int pIr = tid >> 4;            // 0..15
    const int pKq = (tid & 15) * 4;      // 0..60
    const int* adjP0 = &adj[adjBase + (size_t)(i0 + pIr) * NN + pKq];
    const int* adjP1 = adjP0 + 16 * NN;
    const float* s2P = &s2g[bb * NN + pKq];

    // loop-invariant s1 in registers
    const float s1v0 = s1g[bb * NN + i0 + pIr];
    const float s1v1 = s1g[bb * NN + i0 + pIr + 16];
    float lsum0 = 0.f, lsum1 = 0.f;

    // B-fragment base pointers: rows f0+nf*16+l16, col chunk quad*8
    const int f0 = wave * 64;
    const unsigned short* whB0 = &WhT[whtBase + (size_t)(f0 + 0 * 16 + l16) * NN + quad * 8];
    const unsigned short* whB1 = whB0 + (size_t)16 * NN;
    const unsigned short* whB2 = whB0 + (size_t)32 * NN;
    const unsigned short* whB3 = whB0 + (size_t)48 * NN;

    // named prefetch registers, even (A) and odd (B) sets
    uint4 bA0, bA1, bA2, bA3, bA4, bA5, bA6, bA7;
    uint4 bB0, bB1, bB2, bB3, bB4, bB5, bB6, bB7;
    int4 amA0, amA1, amB0, amB1;
    float4 svA, svB;

    // idx 0..3 = nf0..3 (k-half lo), idx 4..7 = nf0..3 (k-half hi)
#define LOADSET(P0, P1, P2, P3, P4, P5, P6, P7, AM0, AM1, SV, J0)             \
    do {                                                                      \
        const int j_ = (J0);                                                  \
        P0 = *(const uint4*)&whB0[j_];                                        \
        P1 = *(const uint4*)&whB1[j_];                                        \
        P2 = *(const uint4*)&whB2[j_];                                        \
        P3 = *(const uint4*)&whB3[j_];                                        \
        P4 = *(const uint4*)&whB0[j_ + 32];                                   \
        P5 = *(const uint4*)&whB1[j_ + 32];                                   \
        P6 = *(const uint4*)&whB2[j_ + 32];                                   \
        P7 = *(const uint4*)&whB3[j_ + 32];                                   \
        AM0 = *(const int4*)&adjP0[j_];                                       \
        AM1 = *(const int4*)&adjP1[j_];                                       \
        SV = *(const float4*)&s2P[j_];                                        \
    } while (0)

#define PCOMP(AM0, AM1, SV, BUF)                                              \
    do {                                                                      \
        float x0 = s1v0 + SV.x, x1 = s1v0 + SV.y;                             \
        float x2 = s1v0 + SV.z, x3 = s1v0 + SV.w;                             \
        x0 = fmaxf(x0, ALPHA * x0);                                           \
        x1 = fmaxf(x1, ALPHA * x1);                                           \
        x2 = fmaxf(x2, ALPHA * x2);                                           \
        x3 = fmaxf(x3, ALPHA * x3);                                           \
        const float p0 = AM0.x > 0 ? __expf(x0) : 0.f;                        \
        const float p1 = AM0.y > 0 ? __expf(x1) : 0.f;                        \
        const float p2 = AM0.z > 0 ? __expf(x2) : 0.f;                        \
        const float p3 = AM0.w > 0 ? __expf(x3) : 0.f;                        \
        uint2 pk;                                                             \
        pk.x = pk2bf(p0, p1);                                                 \
        pk.y = pk2bf(p2, p3);                                                 \
        *(uint2*)&Pb[BUF][pIr][pKq] = pk;                                     \
        lsum0 += (p0 + p1) + (p2 + p3);                                       \
        float y0 = s1v1 + SV.x, y1 = s1v1 + SV.y;                             \
        float y2 = s1v1 + SV.z, y3 = s1v1 + SV.w;                             \
        y0 = fmaxf(y0, ALPHA * y0);                                           \
        y1 = fmaxf(y1, ALPHA * y1);                                           \
        y2 = fmaxf(y2, ALPHA * y2);                                           \
        y3 = fmaxf(y3, ALPHA * y3);                                           \
        const float q0 = AM1.x > 0 ? __expf(y0) : 0.f;                        \
        const float q1 = AM1.y > 0 ? __expf(y1) : 0.f;                        \
        const float q2 = AM1.z > 0 ? __expf(y2) : 0.f;                        \
        const float q3 = AM1.w > 0 ? __expf(y3) : 0.f;                        \
        pk.x = pk2bf(q0, q1);                                                 \
        pk.y = pk2bf(q2, q3);                                                 \
        *(uint2*)&Pb[BUF][pIr + 16][pKq] = pk;                                \
        lsum1 += (q0 + q1) + (q2 + q3);                                       \
    } while (0)

#define MFMA_PH(P0, P1, P2, P3, P4, P5, P6, P7, BUF)                          \
    do {                                                                      \
        bf16x8 af0 = *(const bf16x8*)&Pb[BUF][l16][quad * 8];                 \
        bf16x8 af1 = *(const bf16x8*)&Pb[BUF][16 + l16][quad * 8];            \
        acc[0][0] = __builtin_amdgcn_mfma_f32_16x16x32_bf16(                  \
            af0, *(const bf16x8*)&P0, acc[0][0], 0, 0, 0);                    \
        acc[1][0] = __builtin_amdgcn_mfma_f32_16x16x32_bf16(                  \
            af1, *(const bf16x8*)&P0, acc[1][0], 0, 0, 0);                    \
        acc[0][1] = __builtin_amdgcn_mfma_f32_16x16x32_bf16(                  \
            af0, *(const bf16x8*)&P1, acc[0][1], 0, 0, 0);                    \
        acc[1][1] = __builtin_amdgcn_mfma_f32_16x16x32_bf16(                  \
            af1, *(const bf16x8*)&P1, acc[1][1], 0, 0, 0);                    \
        acc[0][2] = __builtin_amdgcn_mfma_f32_16x16x32_bf16(                  \
            af0, *(const bf16x8*)&P2, acc[0][2], 0, 0, 0);                    \
        acc[1][2] = __builtin_amdgcn_mfma_f32_16x16x32_bf16(                  \
            af1, *(const bf16x8*)&P2, acc[1][2], 0, 0, 0);                    \
        acc[0][3] = __builtin_amdgcn_mfma_f32_16x16x32_bf16(                  \
            af0, *(const bf16x8*)&P3, acc[0][3], 0, 0, 0);                    \
        acc[1][3] = __builtin_amdgcn_mfma_f32_16x16x32_bf16(                  \
            af1, *(const bf16x8*)&P3, acc[1][3], 0, 0, 0);                    \
        af0 = *(const bf16x8*)&Pb[BUF][l16][32 + quad * 8];                   \
        af1 = *(const bf16x8*)&Pb[BUF][16 + l16][32 + quad * 8];              \
        acc[0][0] = __builtin_amdgcn_mfma_f32_16x16x32_bf16(                  \
            af0, *(const bf16x8*)&P4, acc[0][0], 0, 0, 0);                    \
        acc[1][0] = __builtin_amdgcn_mfma_f32_16x16x32_bf16(                  \
            af1, *(const bf16x8*)&P4, acc[1][0], 0, 0, 0);                    \
        acc[0][1] = __builtin_amdgcn_mfma_f32_16x16x32_bf16(                  \
            af0, *(const bf16x8*)&P5, acc[0][1], 0, 0, 0);                    \
        acc[1][1] = __builtin_amdgcn_mfma_f32_16x16x32_bf16(                  \
            af1, *(const bf16x8*)&P5, acc[1][1], 0, 0, 0);                    \
        acc[0][2] = __builtin_amdgcn_mfma_f32_16x16x32_bf16(                  \
            af0, *(const bf16x8*)&P6, acc[0][2], 0, 0, 0);                    \
        acc[1][2] = __builtin_amdgcn_mfma_f32_16x16x32_bf16(                  \
            af1, *(const bf16x8*)&P6, acc[1][2], 0, 0, 0);                    \
        acc[0][3] = __builtin_amdgcn_mfma_f32_16x16x32_bf16(                  \
            af0, *(const bf16x8*)&P7, acc[0][3], 0, 0, 0);                    \
        acc[1][3] = __builtin_amdgcn_mfma_f32_16x16x32_bf16(                  \
            af1, *(const bf16x8*)&P7, acc[1][3], 0, 0, 0);                    \
    } while (0)

    // prologue: set A for tile 0
    LOADSET(bA0, bA1, bA2, bA3, bA4, bA5, bA6, bA7, amA0, amA1, svA, 0);

    for (int tt = 0; tt < NN / 128; ++tt) {
        const int t0 = 2 * tt;
        // ---- even tile: consume set A (buf 0), prefetch set B ----
        PCOMP(amA0, amA1, svA, 0);
        __syncthreads();
        LOADSET(bB0, bB1, bB2, bB3, bB4, bB5, bB6, bB7, amB0, amB1, svB,
                (t0 + 1) * 64);
        MFMA_PH(bA0, bA1, bA2, bA3, bA4, bA5, bA6, bA7, 0);
        // ---- odd tile: consume set B (buf 1), prefetch set A ----
        PCOMP(amB0, amB1, svB, 1);
        __syncthreads();
        if (tt < NN / 128 - 1)
            LOADSET(bA0, bA1, bA2, bA3, bA4, bA5, bA6, bA7, amA0, amA1, svA,
                    (t0 + 2) * 64);
        MFMA_PH(bB0, bB1, bB2, bB3, bB4, bB5, bB6, bB7, 1);
    }
#undef LOADSET
#undef PCOMP
#undef MFMA_PH

    // ---- one-time row-sum reduce (16 threads per row, consecutive lanes) ----
    lsum0 += __shfl_xor(lsum0, 1);
    lsum0 += __shfl_xor(lsum0, 2);
    lsum0 += __shfl_xor(lsum0, 4);
    lsum0 += __shfl_xor(lsum0, 8);
    lsum1 += __shfl_xor(lsum1, 1);
    lsum1 += __shfl_xor(lsum1, 2);
    lsum1 += __shfl_xor(lsum1, 4);
    lsum1 += __shfl_xor(lsum1, 8);
    if ((tid & 15) == 0) {
        l_s[pIr] = 1.0f / lsum0;
        l_s[pIr + 16] = 1.0f / lsum1;
    }
    __syncthreads();

    // ---- epilogue ----
#pragma unroll
    for (int m = 0; m < 2; ++m) {
#pragma unroll
        for (int r = 0; r < 4; ++r) {
            const int row = m * 16 + quad * 4 + r;
            const float inv = l_s[row];
#pragma unroll
            for (int nf = 0; nf < 4; ++nf) {
                out[((size_t)bb * NN + i0 + row) * NF + f0 + nf * 16 + l16] =
                    acc[m][nf][r] * inv;
            }
        }
    }
}

// ---------------------------------------------------------------------------
extern "C" void kernel_launch(void* const* d_in, const int* in_sizes, int n_in,
                              void* d_out, int out_size, void* d_ws, size_t ws_size,
                              hipStream_t stream) {
    const float* h = (const float*)d_in[0];
    const int* adj = (const int*)d_in[1];
    const float* W = (const float*)d_in[2];
    const float* a = (const float*)d_in[3];
    float* out = (float*)d_out;

    unsigned short* WhT = (unsigned short*)d_ws;  // 8.4 MB bf16, [b][f][n]
    float* s1 = (float*)((char*)d_ws + (size_t)NB * NN * NF * sizeof(unsigned short));
    float* s2 = s1 + (size_t)NB * NN;
    unsigned short* WT = (unsigned short*)(s2 + (size_t)NB * NN);  // 128 KB

    k_wt<<<dim3(64), dim3(256), 0, stream>>>(W, WT, s1, s2);
    k_wh<<<dim3((NB * NN / 64) * (NF / 64)), dim3(256), 0, stream>>>(h, WT, a, WhT, s1, s2);
    // grid = NB batches x (NN/32) q-tiles = 512 blocks (one batch per XCD)
    k_attn<<<dim3(NB * (NN / 32)), dim3(256), 0, stream>>>(WhT, adj, s1, s2, out);
}

// Round 12
// 258.848 us; speedup vs baseline: 1.0142x; 1.0142x over previous
//
#include <hip/hip_runtime.h>
#include <cstdint>

#define ALPHA 0.2f

constexpr int NB = 8;
constexpr int NN = 2048;
constexpr int NF = 256;

typedef __attribute__((ext_vector_type(8))) short bf16x8;
typedef __attribute__((ext_vector_type(4))) float f32x4;

__device__ __forceinline__ float bf2f(unsigned short u) {
    union { unsigned int i; float f; } v;
    v.i = ((unsigned int)u) << 16;
    return v.f;
}
__device__ __forceinline__ unsigned short f2bf(float f) {
    union { float f; unsigned int i; } v;
    v.f = f;
    v.i += 0x7fffu + ((v.i >> 16) & 1);  // round-to-nearest-even
    return (unsigned short)(v.i >> 16);
}
// pack two non-negative floats to packed bf16 pair (round-half-up), 3 ops
__device__ __forceinline__ unsigned int pk2bf(float lo, float hi) {
    union { float f; unsigned int u; } a, b;
    a.f = lo; b.f = hi;
    return __builtin_amdgcn_perm(b.u + 0x8000u, a.u + 0x8000u, 0x07060302u);
}

// ---------------------------------------------------------------------------
// Kernel 0: WT[f][k] = bf16(W[k][f]) transpose+cast; also zero s1/s2
// ---------------------------------------------------------------------------
__global__ __launch_bounds__(256) void k_wt(const float* __restrict__ W,
                                            unsigned short* __restrict__ WT,
                                            float* __restrict__ s1,
                                            float* __restrict__ s2) {
    const int t = threadIdx.x;
    const int gid = blockIdx.x * 256 + t;
    s1[gid] = 0.f;
    s2[gid] = 0.f;
    const int k = blockIdx.x * 4 + (t >> 6);
    const int f0 = (t & 63) * 4;
    const float4 w = *(const float4*)&W[k * NF + f0];
    WT[(f0 + 0) * NF + k] = f2bf(w.x);
    WT[(f0 + 1) * NF + k] = f2bf(w.y);
    WT[(f0 + 2) * NF + k] = f2bf(w.z);
    WT[(f0 + 3) * NF + k] = f2bf(w.w);
}

// ---------------------------------------------------------------------------
// Kernel 1: WhT = (h @ W)^T per batch, bf16 MFMA; fused s1/s2 epilogue.
// (unchanged — proven correct, ~6-8 us)
// ---------------------------------------------------------------------------
__global__ __launch_bounds__(256, 4) void k_wh(const float* __restrict__ h,
                                               const unsigned short* __restrict__ WT,
                                               const float* __restrict__ a,
                                               unsigned short* __restrict__ WhT,
                                               float* __restrict__ s1,
                                               float* __restrict__ s2) {
    __shared__ __align__(16) unsigned short As[64][72];  // [row][k] bf16
    __shared__ __align__(16) unsigned short Bs[64][72];  // [f][k]  bf16
    const int tid = threadIdx.x;
    const int lane = tid & 63;
    const int l16 = lane & 15;
    const int quad = lane >> 4;
    const int wave = tid >> 6;

    const int p = blockIdx.x;
    const int xcd = p & 7;
    const int q = p >> 3;                       // 0..127
    const int rowTile = xcd + (q >> 2) * 8;     // 0..255
    const int row0 = rowTile * 64;
    const int col0 = (q & 3) * 64;

    const int bb = row0 >> 11;
    const int n0 = row0 & (NN - 1);
    const int mb = (wave & 1) * 32;
    const int nb = (wave >> 1) * 32;

    f32x4 acc[2][2];
#pragma unroll
    for (int mf = 0; mf < 2; ++mf)
#pragma unroll
        for (int nf = 0; nf < 2; ++nf) acc[mf][nf] = (f32x4){0.f, 0.f, 0.f, 0.f};

    const int r0 = tid >> 4;          // 0..15  (+16 per group)
    const int k4 = (tid & 15) * 4;    // 0..60
    const int f0w = tid >> 3;         // 0..31  (+32 per group)
    const int k8 = (tid & 7) * 8;     // 0..56

    const float* hP = &h[(size_t)(row0 + r0) * NF + k4];
    const unsigned short* wP = &WT[(size_t)(col0 + f0w) * NF + k8];

    float4 h0, h1, h2, h3;
    uint4 wv0, wv1;

#define LOADW(K0)                                                      \
    do {                                                               \
        h0 = *(const float4*)&hP[(size_t)(0 * 16) * NF + (K0)];        \
        h1 = *(const float4*)&hP[(size_t)(1 * 16) * NF + (K0)];        \
        h2 = *(const float4*)&hP[(size_t)(2 * 16) * NF + (K0)];        \
        h3 = *(const float4*)&hP[(size_t)(3 * 16) * NF + (K0)];        \
        wv0 = *(const uint4*)&wP[(K0)];                                \
        wv1 = *(const uint4*)&wP[(size_t)32 * NF + (K0)];              \
    } while (0)

    LOADW(0);

    for (int k0 = 0; k0 < NF; k0 += 64) {
        ushort4 o;
        o.x = f2bf(h0.x); o.y = f2bf(h0.y); o.z = f2bf(h0.z); o.w = f2bf(h0.w);
        *(ushort4*)&As[r0 + 0][k4] = o;
        o.x = f2bf(h1.x); o.y = f2bf(h1.y); o.z = f2bf(h1.z); o.w = f2bf(h1.w);
        *(ushort4*)&As[r0 + 16][k4] = o;
        o.x = f2bf(h2.x); o.y = f2bf(h2.y); o.z = f2bf(h2.z); o.w = f2bf(h2.w);
        *(ushort4*)&As[r0 + 32][k4] = o;
        o.x = f2bf(h3.x); o.y = f2bf(h3.y); o.z = f2bf(h3.z); o.w = f2bf(h3.w);
        *(ushort4*)&As[r0 + 48][k4] = o;
        *(uint4*)&Bs[f0w][k8] = wv0;
        *(uint4*)&Bs[f0w + 32][k8] = wv1;
        __syncthreads();
        if (k0 + 64 < NF) LOADW(k0 + 64);
#pragma unroll
        for (int ks = 0; ks < 64; ks += 32) {
            bf16x8 av[2], bv[2];
#pragma unroll
            for (int mf = 0; mf < 2; ++mf)
                av[mf] = *(const bf16x8*)&As[mb + mf * 16 + l16][ks + quad * 8];
#pragma unroll
            for (int nf = 0; nf < 2; ++nf)
                bv[nf] = *(const bf16x8*)&Bs[nb + nf * 16 + l16][ks + quad * 8];
#pragma unroll
            for (int mf = 0; mf < 2; ++mf)
#pragma unroll
                for (int nf = 0; nf < 2; ++nf)
                    acc[mf][nf] = __builtin_amdgcn_mfma_f32_16x16x32_bf16(
                        av[mf], bv[nf], acc[mf][nf], 0, 0, 0);
        }
        __syncthreads();
    }
#undef LOADW

#pragma unroll
    for (int mf = 0; mf < 2; ++mf) {
#pragma unroll
        for (int nf = 0; nf < 2; ++nf) {
            const size_t f = col0 + nb + nf * 16 + l16;
            const int nr = n0 + mb + mf * 16 + quad * 4;
            ushort4 o;
            o.x = f2bf(acc[mf][nf][0]);
            o.y = f2bf(acc[mf][nf][1]);
            o.z = f2bf(acc[mf][nf][2]);
            o.w = f2bf(acc[mf][nf][3]);
            *(ushort4*)&WhT[((size_t)bb * NF + f) * NN + nr] = o;
        }
    }

    float a1v[2], a2v[2];
#pragma unroll
    for (int nf = 0; nf < 2; ++nf) {
        const int f = col0 + nb + nf * 16 + l16;
        a1v[nf] = a[f];
        a2v[nf] = a[NF + f];
    }
#pragma unroll
    for (int mf = 0; mf < 2; ++mf) {
#pragma unroll
        for (int r = 0; r < 4; ++r) {
            float p1 = acc[mf][0][r] * a1v[0] + acc[mf][1][r] * a1v[1];
            float p2 = acc[mf][0][r] * a2v[0] + acc[mf][1][r] * a2v[1];
            p1 += __shfl_xor(p1, 1); p2 += __shfl_xor(p2, 1);
            p1 += __shfl_xor(p1, 2); p2 += __shfl_xor(p2, 2);
            p1 += __shfl_xor(p1, 4); p2 += __shfl_xor(p2, 4);
            p1 += __shfl_xor(p1, 8); p2 += __shfl_xor(p2, 8);
            if (l16 == 0) {
                const int n = n0 + mb + mf * 16 + quad * 4 + r;
                atomicAdd(&s1[bb * NN + n], p1);
                atomicAdd(&s2[bb * NN + n], p2);
            }
        }
    }
}

// ---------------------------------------------------------------------------
// Kernel 2: fused masked softmax + attn @ Wh.
// Base = r9 (best measured, ~74us): QBLK=32, WhsT LDS staging, prefetch-1-
// tile-ahead regs, two __syncthreads/iter, register row-sums, grid 512.
// NEW: adj is pre-packed into an LDS BITMASK (32 rows x 2048 bits = 8 KB)
// in one upfront coalesced burst. The main loop then has NO adj loads:
// every __syncthreads vmcnt(0) drain now waits only on L2-class WhT/s2
// prefetches (~300cy) instead of the adj HBM/L3 prefetch (~500-900cy).
// adj HBM flow (134 MB total) still happens once, but as overlappable
// streaming at block start, not 32 serialized per-barrier drains.
// ---------------------------------------------------------------------------
__global__ __launch_bounds__(256, 3) void k_attn(const unsigned short* __restrict__ WhT,
                                                 const int* __restrict__ adj,
                                                 const float* __restrict__ s1g,
                                                 const float* __restrict__ s2g,
                                                 float* __restrict__ out) {
    __shared__ __align__(16) unsigned short WhsT[256][72];  // [f][j]
    __shared__ __align__(16) unsigned short Pb[32][72];     // [i][j]
    __shared__ unsigned int adjbits[32][64];                // [i][word] 8 KB
    __shared__ float l_s[32];

    const int tid = threadIdx.x;
    const int lane = tid & 63;
    const int l16 = lane & 15;
    const int quad = lane >> 4;
    const int wave = tid >> 6;
    const int bb = blockIdx.x & 7;           // one batch per XCD
    const int i0 = (blockIdx.x >> 3) * 32;   // q-tile base

    const size_t whtBase = (size_t)bb * NF * NN;
    const size_t adjBase = (size_t)bb * NN * NN;

    // ---- upfront: pack this block's 32 adj rows into LDS bitmask ----
    // wave wv handles rows wv*8..+7; per row 4 chunks of 512 cols;
    // lane reads cols [chunk*512 + lane*8, +8) (2x int4, fully coalesced).
#pragma unroll 2
    for (int r8 = 0; r8 < 8; ++r8) {
        const int row = wave * 8 + r8;
        const int* ap = &adj[adjBase + (size_t)(i0 + row) * NN];
#pragma unroll
        for (int c = 0; c < 4; ++c) {
            const int col = c * 512 + lane * 8;
            const int4 v0 = *(const int4*)&ap[col];
            const int4 v1 = *(const int4*)&ap[col + 4];
            unsigned int b = (v0.x > 0 ? 1u : 0u) | (v0.y > 0 ? 2u : 0u) |
                             (v0.z > 0 ? 4u : 0u) | (v0.w > 0 ? 8u : 0u) |
                             (v1.x > 0 ? 16u : 0u) | (v1.y > 0 ? 32u : 0u) |
                             (v1.z > 0 ? 64u : 0u) | (v1.w > 0 ? 128u : 0u);
            const unsigned int u = b | (__shfl_down(b, 1) << 8) |
                                   (__shfl_down(b, 2) << 16) |
                                   (__shfl_down(b, 3) << 24);
            if ((lane & 3) == 0) adjbits[row][c * 16 + (lane >> 2)] = u;
        }
    }
    __syncthreads();

    f32x4 acc[2][4];
#pragma unroll
    for (int m = 0; m < 2; ++m)
#pragma unroll
        for (int nf = 0; nf < 4; ++nf) acc[m][nf] = (f32x4){0.f, 0.f, 0.f, 0.f};

    // per-thread geometry
    const int whF = tid >> 3;            // 0..255 (it adds 32 per step)
    const int whK = (tid & 7) * 8;       // 0..56
    const int pIr = tid >> 4;            // 0..15 (rows pIr, pIr+16)
    const int pKq = (tid & 15) * 4;      // 0..60
    const int wOff = pKq >> 5;           // 0 or 1
    const int bitsh = pKq & 31;

    const unsigned short* whP = &WhT[whtBase + (size_t)whF * NN + whK];
    const float* s2P = &s2g[bb * NN + pKq];

    // loop-invariant s1 in registers; register row-sum accumulators
    const float s1v0 = s1g[bb * NN + i0 + pIr];
    const float s1v1 = s1g[bb * NN + i0 + pIr + 16];
    float lsum0 = 0.f, lsum1 = 0.f;

    // named prefetch registers (WhT + s2 only — adj now lives in LDS)
    uint4 w0, w1, w2, w3, w4, w5, w6, w7;
    float4 sv0;

#define LOAD_TILE(J0)                                                         \
    do {                                                                      \
        const int j0_ = (J0);                                                 \
        w0 = *(const uint4*)&whP[(size_t)(0 * 32) * NN + j0_];                \
        w1 = *(const uint4*)&whP[(size_t)(1 * 32) * NN + j0_];                \
        w2 = *(const uint4*)&whP[(size_t)(2 * 32) * NN + j0_];                \
        w3 = *(const uint4*)&whP[(size_t)(3 * 32) * NN + j0_];                \
        w4 = *(const uint4*)&whP[(size_t)(4 * 32) * NN + j0_];                \
        w5 = *(const uint4*)&whP[(size_t)(5 * 32) * NN + j0_];                \
        w6 = *(const uint4*)&whP[(size_t)(6 * 32) * NN + j0_];                \
        w7 = *(const uint4*)&whP[(size_t)(7 * 32) * NN + j0_];                \
        sv0 = *(const float4*)&s2P[j0_];                                      \
    } while (0)

    LOAD_TILE(0);

    for (int t = 0; t < NN / 64; ++t) {
        // ---- prefetched WhT -> LDS ----
        *(uint4*)&WhsT[whF + 0 * 32][whK] = w0;
        *(uint4*)&WhsT[whF + 1 * 32][whK] = w1;
        *(uint4*)&WhsT[whF + 2 * 32][whK] = w2;
        *(uint4*)&WhsT[whF + 3 * 32][whK] = w3;
        *(uint4*)&WhsT[whF + 4 * 32][whK] = w4;
        *(uint4*)&WhsT[whF + 5 * 32][whK] = w5;
        *(uint4*)&WhsT[whF + 6 * 32][whK] = w6;
        *(uint4*)&WhsT[whF + 7 * 32][whK] = w7;
        // ---- adj bits from LDS (broadcast across 8 threads/word) ----
        const unsigned int m0 = adjbits[pIr][2 * t + wOff] >> bitsh;
        const unsigned int m1 = adjbits[pIr + 16][2 * t + wOff] >> bitsh;
        // ---- P: rows pIr (m0) and pIr+16 (m1), 4 j's each ----
        {
            float x0 = s1v0 + sv0.x, x1 = s1v0 + sv0.y;
            float x2 = s1v0 + sv0.z, x3 = s1v0 + sv0.w;
            x0 = fmaxf(x0, ALPHA * x0);
            x1 = fmaxf(x1, ALPHA * x1);
            x2 = fmaxf(x2, ALPHA * x2);
            x3 = fmaxf(x3, ALPHA * x3);
            const float p0 = (m0 & 1u) ? __expf(x0) : 0.f;
            const float p1 = (m0 & 2u) ? __expf(x1) : 0.f;
            const float p2 = (m0 & 4u) ? __expf(x2) : 0.f;
            const float p3 = (m0 & 8u) ? __expf(x3) : 0.f;
            uint2 pk;
            pk.x = pk2bf(p0, p1);
            pk.y = pk2bf(p2, p3);
            *(uint2*)&Pb[pIr][pKq] = pk;
            lsum0 += (p0 + p1) + (p2 + p3);
        }
        {
            float x0 = s1v1 + sv0.x, x1 = s1v1 + sv0.y;
            float x2 = s1v1 + sv0.z, x3 = s1v1 + sv0.w;
            x0 = fmaxf(x0, ALPHA * x0);
            x1 = fmaxf(x1, ALPHA * x1);
            x2 = fmaxf(x2, ALPHA * x2);
            x3 = fmaxf(x3, ALPHA * x3);
            const float p0 = (m1 & 1u) ? __expf(x0) : 0.f;
            const float p1 = (m1 & 2u) ? __expf(x1) : 0.f;
            const float p2 = (m1 & 4u) ? __expf(x2) : 0.f;
            const float p3 = (m1 & 8u) ? __expf(x3) : 0.f;
            uint2 pk;
            pk.x = pk2bf(p0, p1);
            pk.y = pk2bf(p2, p3);
            *(uint2*)&Pb[pIr + 16][pKq] = pk;
            lsum1 += (p0 + p1) + (p2 + p3);
        }
        __syncthreads();
        // ---- issue next tile's loads (L2-class; fly during MFMA) ----
        if (t + 1 < NN / 64) LOAD_TILE((t + 1) * 64);
        // ---- MFMA: out[32 x 64f per wave] += P[32 x 64j] * WhsT^T ----
        const int f0 = wave * 64;
#pragma unroll
        for (int k0 = 0; k0 < 64; k0 += 32) {
            bf16x8 af[2];
#pragma unroll
            for (int m = 0; m < 2; ++m)
                af[m] = *(const bf16x8*)&Pb[m * 16 + l16][k0 + quad * 8];
#pragma unroll
            for (int nf = 0; nf < 4; ++nf) {
                const bf16x8 bfr =
                    *(const bf16x8*)&WhsT[f0 + nf * 16 + l16][k0 + quad * 8];
#pragma unroll
                for (int m = 0; m < 2; ++m)
                    acc[m][nf] = __builtin_amdgcn_mfma_f32_16x16x32_bf16(
                        af[m], bfr, acc[m][nf], 0, 0, 0);
            }
        }
        __syncthreads();
    }
#undef LOAD_TILE

    // ---- one-time row-sum reduce (16 threads per row, consecutive lanes) ----
    lsum0 += __shfl_xor(lsum0, 1);
    lsum0 += __shfl_xor(lsum0, 2);
    lsum0 += __shfl_xor(lsum0, 4);
    lsum0 += __shfl_xor(lsum0, 8);
    lsum1 += __shfl_xor(lsum1, 1);
    lsum1 += __shfl_xor(lsum1, 2);
    lsum1 += __shfl_xor(lsum1, 4);
    lsum1 += __shfl_xor(lsum1, 8);
    if ((tid & 15) == 0) {
        l_s[pIr] = 1.0f / lsum0;
        l_s[pIr + 16] = 1.0f / lsum1;
    }
    __syncthreads();

    // ---- epilogue ----
    const int f0 = wave * 64;
#pragma unroll
    for (int m = 0; m < 2; ++m) {
#pragma unroll
        for (int r = 0; r < 4; ++r) {
            const int row = m * 16 + quad * 4 + r;
            const float inv = l_s[row];
#pragma unroll
            for (int nf = 0; nf < 4; ++nf) {
                out[((size_t)bb * NN + i0 + row) * NF + f0 + nf * 16 + l16] =
                    acc[m][nf][r] * inv;
            }
        }
    }
}

// ---------------------------------------------------------------------------
extern "C" void kernel_launch(void* const* d_in, const int* in_sizes, int n_in,
                              void* d_out, int out_size, void* d_ws, size_t ws_size,
                              hipStream_t stream) {
    const float* h = (const float*)d_in[0];
    const int* adj = (const int*)d_in[1];
    const float* W = (const float*)d_in[2];
    const float* a = (const float*)d_in[3];
    float* out = (float*)d_out;

    unsigned short* WhT = (unsigned short*)d_ws;  // 8.4 MB bf16, [b][f][n]
    float* s1 = (float*)((char*)d_ws + (size_t)NB * NN * NF * sizeof(unsigned short));
    float* s2 = s1 + (size_t)NB * NN;
    unsigned short* WT = (unsigned short*)(s2 + (size_t)NB * NN);  // 128 KB

    k_wt<<<dim3(64), dim3(256), 0, stream>>>(W, WT, s1, s2);
    k_wh<<<dim3((NB * NN / 64) * (NF / 64)), dim3(256), 0, stream>>>(h, WT, a, WhT, s1, s2);
    // grid = NB batches x (NN/32) q-tiles = 512 blocks (one batch per XCD)
    k_attn<<<dim3(NB * (NN / 32)), dim3(256), 0, stream>>>(WhT, adj, s1, s2, out);
}

// Round 13
// 227.689 us; speedup vs baseline: 1.1530x; 1.1368x over previous
//
#include <hip/hip_runtime.h>
#include <cstdint>

#define ALPHA 0.2f

constexpr int NB = 8;
constexpr int NN = 2048;
constexpr int NF = 256;

typedef __attribute__((ext_vector_type(8))) short bf16x8;
typedef __attribute__((ext_vector_type(4))) float f32x4;

__device__ __forceinline__ float bf2f(unsigned short u) {
    union { unsigned int i; float f; } v;
    v.i = ((unsigned int)u) << 16;
    return v.f;
}
__device__ __forceinline__ unsigned short f2bf(float f) {
    union { float f; unsigned int i; } v;
    v.f = f;
    v.i += 0x7fffu + ((v.i >> 16) & 1);  // round-to-nearest-even
    return (unsigned short)(v.i >> 16);
}
// pack two non-negative floats to packed bf16 pair (round-half-up), 3 ops
__device__ __forceinline__ unsigned int pk2bf(float lo, float hi) {
    union { float f; unsigned int u; } a, b;
    a.f = lo; b.f = hi;
    return __builtin_amdgcn_perm(b.u + 0x8000u, a.u + 0x8000u, 0x07060302u);
}

// ---------------------------------------------------------------------------
// Kernel 0: WT[f][k] = bf16(W[k][f]) transpose+cast; also zero s1/s2
// ---------------------------------------------------------------------------
__global__ __launch_bounds__(256) void k_wt(const float* __restrict__ W,
                                            unsigned short* __restrict__ WT,
                                            float* __restrict__ s1,
                                            float* __restrict__ s2) {
    const int t = threadIdx.x;
    const int gid = blockIdx.x * 256 + t;
    s1[gid] = 0.f;
    s2[gid] = 0.f;
    const int k = blockIdx.x * 4 + (t >> 6);
    const int f0 = (t & 63) * 4;
    const float4 w = *(const float4*)&W[k * NF + f0];
    WT[(f0 + 0) * NF + k] = f2bf(w.x);
    WT[(f0 + 1) * NF + k] = f2bf(w.y);
    WT[(f0 + 2) * NF + k] = f2bf(w.z);
    WT[(f0 + 3) * NF + k] = f2bf(w.w);
}

// ---------------------------------------------------------------------------
// Kernel 1: WhT = (h @ W)^T per batch, bf16 MFMA; fused s1/s2 epilogue.
// (unchanged — proven correct, ~6-8 us)
// ---------------------------------------------------------------------------
__global__ __launch_bounds__(256, 4) void k_wh(const float* __restrict__ h,
                                               const unsigned short* __restrict__ WT,
                                               const float* __restrict__ a,
                                               unsigned short* __restrict__ WhT,
                                               float* __restrict__ s1,
                                               float* __restrict__ s2) {
    __shared__ __align__(16) unsigned short As[64][72];  // [row][k] bf16
    __shared__ __align__(16) unsigned short Bs[64][72];  // [f][k]  bf16
    const int tid = threadIdx.x;
    const int lane = tid & 63;
    const int l16 = lane & 15;
    const int quad = lane >> 4;
    const int wave = tid >> 6;

    const int p = blockIdx.x;
    const int xcd = p & 7;
    const int q = p >> 3;                       // 0..127
    const int rowTile = xcd + (q >> 2) * 8;     // 0..255
    const int row0 = rowTile * 64;
    const int col0 = (q & 3) * 64;

    const int bb = row0 >> 11;
    const int n0 = row0 & (NN - 1);
    const int mb = (wave & 1) * 32;
    const int nb = (wave >> 1) * 32;

    f32x4 acc[2][2];
#pragma unroll
    for (int mf = 0; mf < 2; ++mf)
#pragma unroll
        for (int nf = 0; nf < 2; ++nf) acc[mf][nf] = (f32x4){0.f, 0.f, 0.f, 0.f};

    const int r0 = tid >> 4;          // 0..15  (+16 per group)
    const int k4 = (tid & 15) * 4;    // 0..60
    const int f0w = tid >> 3;         // 0..31  (+32 per group)
    const int k8 = (tid & 7) * 8;     // 0..56

    const float* hP = &h[(size_t)(row0 + r0) * NF + k4];
    const unsigned short* wP = &WT[(size_t)(col0 + f0w) * NF + k8];

    float4 h0, h1, h2, h3;
    uint4 wv0, wv1;

#define LOADW(K0)                                                      \
    do {                                                               \
        h0 = *(const float4*)&hP[(size_t)(0 * 16) * NF + (K0)];        \
        h1 = *(const float4*)&hP[(size_t)(1 * 16) * NF + (K0)];        \
        h2 = *(const float4*)&hP[(size_t)(2 * 16) * NF + (K0)];        \
        h3 = *(const float4*)&hP[(size_t)(3 * 16) * NF + (K0)];        \
        wv0 = *(const uint4*)&wP[(K0)];                                \
        wv1 = *(const uint4*)&wP[(size_t)32 * NF + (K0)];              \
    } while (0)

    LOADW(0);

    for (int k0 = 0; k0 < NF; k0 += 64) {
        ushort4 o;
        o.x = f2bf(h0.x); o.y = f2bf(h0.y); o.z = f2bf(h0.z); o.w = f2bf(h0.w);
        *(ushort4*)&As[r0 + 0][k4] = o;
        o.x = f2bf(h1.x); o.y = f2bf(h1.y); o.z = f2bf(h1.z); o.w = f2bf(h1.w);
        *(ushort4*)&As[r0 + 16][k4] = o;
        o.x = f2bf(h2.x); o.y = f2bf(h2.y); o.z = f2bf(h2.z); o.w = f2bf(h2.w);
        *(ushort4*)&As[r0 + 32][k4] = o;
        o.x = f2bf(h3.x); o.y = f2bf(h3.y); o.z = f2bf(h3.z); o.w = f2bf(h3.w);
        *(ushort4*)&As[r0 + 48][k4] = o;
        *(uint4*)&Bs[f0w][k8] = wv0;
        *(uint4*)&Bs[f0w + 32][k8] = wv1;
        __syncthreads();
        if (k0 + 64 < NF) LOADW(k0 + 64);
#pragma unroll
        for (int ks = 0; ks < 64; ks += 32) {
            bf16x8 av[2], bv[2];
#pragma unroll
            for (int mf = 0; mf < 2; ++mf)
                av[mf] = *(const bf16x8*)&As[mb + mf * 16 + l16][ks + quad * 8];
#pragma unroll
            for (int nf = 0; nf < 2; ++nf)
                bv[nf] = *(const bf16x8*)&Bs[nb + nf * 16 + l16][ks + quad * 8];
#pragma unroll
            for (int mf = 0; mf < 2; ++mf)
#pragma unroll
                for (int nf = 0; nf < 2; ++nf)
                    acc[mf][nf] = __builtin_amdgcn_mfma_f32_16x16x32_bf16(
                        av[mf], bv[nf], acc[mf][nf], 0, 0, 0);
        }
        __syncthreads();
    }
#undef LOADW

#pragma unroll
    for (int mf = 0; mf < 2; ++mf) {
#pragma unroll
        for (int nf = 0; nf < 2; ++nf) {
            const size_t f = col0 + nb + nf * 16 + l16;
            const int nr = n0 + mb + mf * 16 + quad * 4;
            ushort4 o;
            o.x = f2bf(acc[mf][nf][0]);
            o.y = f2bf(acc[mf][nf][1]);
            o.z = f2bf(acc[mf][nf][2]);
            o.w = f2bf(acc[mf][nf][3]);
            *(ushort4*)&WhT[((size_t)bb * NF + f) * NN + nr] = o;
        }
    }

    float a1v[2], a2v[2];
#pragma unroll
    for (int nf = 0; nf < 2; ++nf) {
        const int f = col0 + nb + nf * 16 + l16;
        a1v[nf] = a[f];
        a2v[nf] = a[NF + f];
    }
#pragma unroll
    for (int mf = 0; mf < 2; ++mf) {
#pragma unroll
        for (int r = 0; r < 4; ++r) {
            float p1 = acc[mf][0][r] * a1v[0] + acc[mf][1][r] * a1v[1];
            float p2 = acc[mf][0][r] * a2v[0] + acc[mf][1][r] * a2v[1];
            p1 += __shfl_xor(p1, 1); p2 += __shfl_xor(p2, 1);
            p1 += __shfl_xor(p1, 2); p2 += __shfl_xor(p2, 2);
            p1 += __shfl_xor(p1, 4); p2 += __shfl_xor(p2, 4);
            p1 += __shfl_xor(p1, 8); p2 += __shfl_xor(p2, 8);
            if (l16 == 0) {
                const int n = n0 + mb + mf * 16 + quad * 4 + r;
                atomicAdd(&s1[bb * NN + n], p1);
                atomicAdd(&s2[bb * NN + n], p2);
            }
        }
    }
}

// ---------------------------------------------------------------------------
// Kernel 2: fused masked softmax + attn @ Wh.
// r9 template (best measured: QBLK=32, WhsT staging, prefetch-1-ahead,
// two __syncthreads/iter, register row-sums, grid 512, batch/XCD) with
// JBLK 64 -> 128: HALF the iterations (32->16). Per-iteration fixed
// overhead (two full-drain barriers + load-latency exposure, ~half of
// each iteration) is paid 16x instead of 32x; total work unchanged.
// LDS 78.5 KB -> 2 blocks/CU (same as r9). Pad 128->136 keeps the
// row-stride = 4 mod 32 dwords (2-way bank aliasing, free).
// ---------------------------------------------------------------------------
__global__ __launch_bounds__(256, 2) void k_attn(const unsigned short* __restrict__ WhT,
                                                 const int* __restrict__ adj,
                                                 const float* __restrict__ s1g,
                                                 const float* __restrict__ s2g,
                                                 float* __restrict__ out) {
    __shared__ __align__(16) unsigned short WhsT[256][136];  // [f][j] 69.6 KB
    __shared__ __align__(16) unsigned short Pb[32][136];     // [i][j] 8.7 KB
    __shared__ float l_s[32];

    const int tid = threadIdx.x;
    const int lane = tid & 63;
    const int l16 = lane & 15;
    const int quad = lane >> 4;
    const int wave = tid >> 6;
    const int bb = blockIdx.x & 7;           // one batch per XCD
    const int i0 = (blockIdx.x >> 3) * 32;   // q-tile base

    f32x4 acc[2][4];
#pragma unroll
    for (int m = 0; m < 2; ++m)
#pragma unroll
        for (int nf = 0; nf < 4; ++nf) acc[m][nf] = (f32x4){0.f, 0.f, 0.f, 0.f};

    const size_t whtBase = (size_t)bb * NF * NN;
    const size_t adjBase = (size_t)bb * NN * NN;

    // staging geometry: 16 uint4/thread cover WhsT[256][128]
    const int whF = tid >> 4;            // 0..15 (+16 per round, 16 rounds)
    const int whKj = (tid & 15) * 8;     // j-offset 0..120
    // P geometry: thread covers rows {pIr, pIr+16}, 8 j's at pKq..pKq+7
    const int pIr = tid >> 4;            // 0..15
    const int pKq = (tid & 15) * 8;      // 0..120

    const unsigned short* whP = &WhT[whtBase + (size_t)whF * NN + whKj];
    const int* adjP0 = &adj[adjBase + (size_t)(i0 + pIr) * NN + pKq];
    const int* adjP1 = adjP0 + 16 * NN;
    const float* s2P = &s2g[bb * NN + pKq];

    // loop-invariant s1 in registers; register row-sum accumulators
    const float s1v0 = s1g[bb * NN + i0 + pIr];
    const float s1v1 = s1g[bb * NN + i0 + pIr + 16];
    float lsum0 = 0.f, lsum1 = 0.f;

    // named prefetch registers (one full 128-j tile ahead)
    uint4 w0, w1, w2, w3, w4, w5, w6, w7, w8, w9, wa, wb, wc, wd, we, wf;
    int4 am0a, am0b, am1a, am1b;
    float4 sva, svb;

#define LOAD_TILE(J0)                                                         \
    do {                                                                      \
        const int j0_ = (J0);                                                 \
        w0 = *(const uint4*)&whP[(size_t)(0 * 16) * NN + j0_];                \
        w1 = *(const uint4*)&whP[(size_t)(1 * 16) * NN + j0_];                \
        w2 = *(const uint4*)&whP[(size_t)(2 * 16) * NN + j0_];                \
        w3 = *(const uint4*)&whP[(size_t)(3 * 16) * NN + j0_];                \
        w4 = *(const uint4*)&whP[(size_t)(4 * 16) * NN + j0_];                \
        w5 = *(const uint4*)&whP[(size_t)(5 * 16) * NN + j0_];                \
        w6 = *(const uint4*)&whP[(size_t)(6 * 16) * NN + j0_];                \
        w7 = *(const uint4*)&whP[(size_t)(7 * 16) * NN + j0_];                \
        w8 = *(const uint4*)&whP[(size_t)(8 * 16) * NN + j0_];                \
        w9 = *(const uint4*)&whP[(size_t)(9 * 16) * NN + j0_];                \
        wa = *(const uint4*)&whP[(size_t)(10 * 16) * NN + j0_];               \
        wb = *(const uint4*)&whP[(size_t)(11 * 16) * NN + j0_];               \
        wc = *(const uint4*)&whP[(size_t)(12 * 16) * NN + j0_];               \
        wd = *(const uint4*)&whP[(size_t)(13 * 16) * NN + j0_];               \
        we = *(const uint4*)&whP[(size_t)(14 * 16) * NN + j0_];               \
        wf = *(const uint4*)&whP[(size_t)(15 * 16) * NN + j0_];               \
        am0a = *(const int4*)&adjP0[j0_];                                     \
        am0b = *(const int4*)&adjP0[j0_ + 4];                                 \
        am1a = *(const int4*)&adjP1[j0_];                                     \
        am1b = *(const int4*)&adjP1[j0_ + 4];                                 \
        sva = *(const float4*)&s2P[j0_];                                      \
        svb = *(const float4*)&s2P[j0_ + 4];                                  \
    } while (0)

    // P for one row: 8 j's -> one uint4 Pb write + running sum
#define PROW(S1V, AMA, AMB, ROW, LSUM)                                        \
    do {                                                                      \
        float x0 = (S1V) + sva.x, x1 = (S1V) + sva.y;                         \
        float x2 = (S1V) + sva.z, x3 = (S1V) + sva.w;                         \
        float x4 = (S1V) + svb.x, x5 = (S1V) + svb.y;                         \
        float x6 = (S1V) + svb.z, x7 = (S1V) + svb.w;                         \
        x0 = fmaxf(x0, ALPHA * x0);                                           \
        x1 = fmaxf(x1, ALPHA * x1);                                           \
        x2 = fmaxf(x2, ALPHA * x2);                                           \
        x3 = fmaxf(x3, ALPHA * x3);                                           \
        x4 = fmaxf(x4, ALPHA * x4);                                           \
        x5 = fmaxf(x5, ALPHA * x5);                                           \
        x6 = fmaxf(x6, ALPHA * x6);                                           \
        x7 = fmaxf(x7, ALPHA * x7);                                           \
        const float p0 = AMA.x > 0 ? __expf(x0) : 0.f;                        \
        const float p1 = AMA.y > 0 ? __expf(x1) : 0.f;                        \
        const float p2 = AMA.z > 0 ? __expf(x2) : 0.f;                        \
        const float p3 = AMA.w > 0 ? __expf(x3) : 0.f;                        \
        const float p4 = AMB.x > 0 ? __expf(x4) : 0.f;                        \
        const float p5 = AMB.y > 0 ? __expf(x5) : 0.f;                        \
        const float p6 = AMB.z > 0 ? __expf(x6) : 0.f;                        \
        const float p7 = AMB.w > 0 ? __expf(x7) : 0.f;                        \
        uint4 pk;                                                             \
        pk.x = pk2bf(p0, p1);                                                 \
        pk.y = pk2bf(p2, p3);                                                 \
        pk.z = pk2bf(p4, p5);                                                 \
        pk.w = pk2bf(p6, p7);                                                 \
        *(uint4*)&Pb[ROW][pKq] = pk;                                          \
        LSUM += ((p0 + p1) + (p2 + p3)) + ((p4 + p5) + (p6 + p7));            \
    } while (0)

    LOAD_TILE(0);

    for (int t = 0; t < NN / 128; ++t) {
        // ---- prefetched WhT -> LDS (16 rounds of 16 rows) ----
        *(uint4*)&WhsT[whF + 0 * 16][whKj] = w0;
        *(uint4*)&WhsT[whF + 1 * 16][whKj] = w1;
        *(uint4*)&WhsT[whF + 2 * 16][whKj] = w2;
        *(uint4*)&WhsT[whF + 3 * 16][whKj] = w3;
        *(uint4*)&WhsT[whF + 4 * 16][whKj] = w4;
        *(uint4*)&WhsT[whF + 5 * 16][whKj] = w5;
        *(uint4*)&WhsT[whF + 6 * 16][whKj] = w6;
        *(uint4*)&WhsT[whF + 7 * 16][whKj] = w7;
        *(uint4*)&WhsT[whF + 8 * 16][whKj] = w8;
        *(uint4*)&WhsT[whF + 9 * 16][whKj] = w9;
        *(uint4*)&WhsT[whF + 10 * 16][whKj] = wa;
        *(uint4*)&WhsT[whF + 11 * 16][whKj] = wb;
        *(uint4*)&WhsT[whF + 12 * 16][whKj] = wc;
        *(uint4*)&WhsT[whF + 13 * 16][whKj] = wd;
        *(uint4*)&WhsT[whF + 14 * 16][whKj] = we;
        *(uint4*)&WhsT[whF + 15 * 16][whKj] = wf;
        // ---- P: rows pIr and pIr+16, 8 j's each ----
        PROW(s1v0, am0a, am0b, pIr, lsum0);
        PROW(s1v1, am1a, am1b, pIr + 16, lsum1);
        __syncthreads();
        // ---- issue next tile's loads (fly during MFMA + barrier) ----
        if (t + 1 < NN / 128) LOAD_TILE((t + 1) * 128);
        // ---- MFMA: out[32 x 64f per wave] += P[32 x 128j] * WhsT^T ----
        const int f0 = wave * 64;
#pragma unroll
        for (int k0 = 0; k0 < 128; k0 += 32) {
            bf16x8 af[2];
#pragma unroll
            for (int m = 0; m < 2; ++m)
                af[m] = *(const bf16x8*)&Pb[m * 16 + l16][k0 + quad * 8];
#pragma unroll
            for (int nf = 0; nf < 4; ++nf) {
                const bf16x8 bfr =
                    *(const bf16x8*)&WhsT[f0 + nf * 16 + l16][k0 + quad * 8];
#pragma unroll
                for (int m = 0; m < 2; ++m)
                    acc[m][nf] = __builtin_amdgcn_mfma_f32_16x16x32_bf16(
                        af[m], bfr, acc[m][nf], 0, 0, 0);
            }
        }
        __syncthreads();
    }
#undef LOAD_TILE
#undef PROW

    // ---- one-time row-sum reduce (16 threads per row, consecutive lanes) ----
    lsum0 += __shfl_xor(lsum0, 1);
    lsum0 += __shfl_xor(lsum0, 2);
    lsum0 += __shfl_xor(lsum0, 4);
    lsum0 += __shfl_xor(lsum0, 8);
    lsum1 += __shfl_xor(lsum1, 1);
    lsum1 += __shfl_xor(lsum1, 2);
    lsum1 += __shfl_xor(lsum1, 4);
    lsum1 += __shfl_xor(lsum1, 8);
    if ((tid & 15) == 0) {
        l_s[pIr] = 1.0f / lsum0;
        l_s[pIr + 16] = 1.0f / lsum1;
    }
    __syncthreads();

    // ---- epilogue ----
    const int f0 = wave * 64;
#pragma unroll
    for (int m = 0; m < 2; ++m) {
#pragma unroll
        for (int r = 0; r < 4; ++r) {
            const int row = m * 16 + quad * 4 + r;
            const float inv = l_s[row];
#pragma unroll
            for (int nf = 0; nf < 4; ++nf) {
                out[((size_t)bb * NN + i0 + row) * NF + f0 + nf * 16 + l16] =
                    acc[m][nf][r] * inv;
            }
        }
    }
}

// ---------------------------------------------------------------------------
extern "C" void kernel_launch(void* const* d_in, const int* in_sizes, int n_in,
                              void* d_out, int out_size, void* d_ws, size_t ws_size,
                              hipStream_t stream) {
    const float* h = (const float*)d_in[0];
    const int* adj = (const int*)d_in[1];
    const float* W = (const float*)d_in[2];
    const float* a = (const float*)d_in[3];
    float* out = (float*)d_out;

    unsigned short* WhT = (unsigned short*)d_ws;  // 8.4 MB bf16, [b][f][n]
    float* s1 = (float*)((char*)d_ws + (size_t)NB * NN * NF * sizeof(unsigned short));
    float* s2 = s1 + (size_t)NB * NN;
    unsigned short* WT = (unsigned short*)(s2 + (size_t)NB * NN);  // 128 KB

    k_wt<<<dim3(64), dim3(256), 0, stream>>>(W, WT, s1, s2);
    k_wh<<<dim3((NB * NN / 64) * (NF / 64)), dim3(256), 0, stream>>>(h, WT, a, WhT, s1, s2);
    // grid = NB batches x (NN/32) q-tiles = 512 blocks (one batch per XCD)
    k_attn<<<dim3(NB * (NN / 32)), dim3(256), 0, stream>>>(WhT, adj, s1, s2, out);
}